// Round 4
// baseline (589.885 us; speedup 1.0000x reference)
//
#include <hip/hip_runtime.h>
#include <hip/hip_bf16.h>
#include <math.h>

// Problem constants
#define HID  1024
#define NEXP 8
#define CAP  1536
#define NTOK 4096   // B*S

// Output layout (fp32), concatenated flat in reference return order:
//   dispatch [4096,8,1536] | combine [4096,8,1536] | router_probs [4096,8] | aux [1]
#define DISP_OFF 0ull
#define COMB_OFF 50331648ull
#define RP_OFF   100663296ull
#define AUX_OFF  100696064ull

typedef float f32x4 __attribute__((ext_vector_type(4)));
typedef short s16x8 __attribute__((ext_vector_type(8)));

// ws layout (floats): part[16][4096][8] | cnt (int) | worklist[512] (uint)
#define PART_F   (16 * 4096 * 8)
#define MAXFIX   512
#define PGAP_TAU 1e-4f    // rank2/rank3 prob-gap below which we fp32-recompute

// fp32 -> (bf16 hi, bf16 mid) split of 8 values (RNE both)
__device__ __forceinline__ void cvt8(const float4 v0, const float4 v1, s16x8& hi, s16x8& mi)
{
    float f[8] = {v0.x, v0.y, v0.z, v0.w, v1.x, v1.y, v1.z, v1.w};
#pragma unroll
    for (int i = 0; i < 8; ++i) {
        __hip_bfloat16 h = __float2bfloat16(f[i]);
        float fh = __bfloat162float(h);
        __hip_bfloat16 m = __float2bfloat16(f[i] - fh);
        hi[i] = (short)__builtin_bit_cast(unsigned short, h);
        mi[i] = (short)__builtin_bit_cast(unsigned short, m);
    }
}

// ---------------- Fused: MFMA split-bf16 GEMM+router-partials (blocks 0..255)
//                  + 402.7 MB zero-fill (blocks 256..511) ----------------
// h = relu(x @ w1^T + b1); partial logits per 64-col slice -> ws.part
__global__ __launch_bounds__(256, 2) void fused_kernel(
    const float* __restrict__ A,    // x  [4096,1024]
    const float* __restrict__ W,    // w1 [1024,1024] row=out-dim, K-contiguous
    const float* __restrict__ B1,   // b1 [1024]
    const float* __restrict__ W2,   // w2 [8,1024]
    float* __restrict__ ws,
    float* __restrict__ out)
{
    const int tid = threadIdx.x;
    const int bid = blockIdx.x;

    // LDS: A-hi/mid, B-hi/mid tiles [128 rows][32 k] bf16 = 8 KB each (32 KB)
    __shared__ s16x8 LAh[512], LAm[512], LBh[512], LBm[512];

    if (bid >= 256) {
        // ---- zero role: 256 blocks * 256 thr * 384 f32x4 = 402.7 MB ----
        const int zid = bid - 256;
        if (zid == 0 && tid == 0) ((int*)(ws + PART_F))[0] = 0;   // fixup counter
        f32x4* p = (f32x4*)out + (size_t)zid * 98304 + tid;
        f32x4 z = (f32x4)0.0f;
#pragma unroll 8
        for (int i = 0; i < 384; ++i) { __builtin_nontemporal_store(z, p); p += 256; }
        return;
    }

    // ---- GEMM role: tile 128x128, 4 waves in 2x2, BK=32 ----
    const int n0 = (bid & 7) * 128;
    const int m0 = (bid >> 3) * 128;
    const int wave = tid >> 6, lane = tid & 63;
    const int wr = wave >> 1, wc = wave & 1;
    const int fr = lane & 15, fk = lane >> 4;
    const int lr = tid >> 2, lkg = tid & 3;    // loader: row, k-group

    const float* Ap = A + (size_t)(m0 + lr) * HID + lkg * 8;
    const float* Bp = W + (size_t)(n0 + lr) * HID + lkg * 8;

    f32x4 acc[4][4];
#pragma unroll
    for (int i = 0; i < 4; ++i)
#pragma unroll
        for (int j = 0; j < 4; ++j) acc[i][j] = (f32x4)0.0f;

    // prologue: load K-tile 0 (each thread: rows lr & lr+64, 8 k-floats each, A and B)
    float4 la0 = *(const float4*)(Ap),         la1 = *(const float4*)(Ap + 4);
    float4 la2 = *(const float4*)(Ap + 65536), la3 = *(const float4*)(Ap + 65540);
    float4 lb0 = *(const float4*)(Bp),         lb1 = *(const float4*)(Bp + 4);
    float4 lb2 = *(const float4*)(Bp + 65536), lb3 = *(const float4*)(Bp + 65540);

    for (int k0 = 0; k0 < 32; ++k0) {
        s16x8 ah0, am0, ah1, am1, bh0, bm0, bh1, bm1;
        cvt8(la0, la1, ah0, am0);
        cvt8(la2, la3, ah1, am1);
        cvt8(lb0, lb1, bh0, bm0);
        cvt8(lb2, lb3, bh1, bm1);
        if (k0 + 1 < 32) {     // issue next tile's loads; land during MFMA phase
            const int off = (k0 + 1) * 32;
            la0 = *(const float4*)(Ap + off);         la1 = *(const float4*)(Ap + off + 4);
            la2 = *(const float4*)(Ap + off + 65536); la3 = *(const float4*)(Ap + off + 65540);
            lb0 = *(const float4*)(Bp + off);         lb1 = *(const float4*)(Bp + off + 4);
            lb2 = *(const float4*)(Bp + off + 65536); lb3 = *(const float4*)(Bp + off + 65540);
        }
        __syncthreads();                       // prev iter's frag reads done
        LAh[lr * 4 + lkg] = ah0;        LAm[lr * 4 + lkg] = am0;
        LAh[(lr + 64) * 4 + lkg] = ah1; LAm[(lr + 64) * 4 + lkg] = am1;
        LBh[lr * 4 + lkg] = bh0;        LBm[lr * 4 + lkg] = bm0;
        LBh[(lr + 64) * 4 + lkg] = bh1; LBm[(lr + 64) * 4 + lkg] = bm1;
        __syncthreads();                       // tiles visible

        s16x8 fah[4], fam[4], fbh[4], fbm[4];
#pragma unroll
        for (int i = 0; i < 4; ++i) {
            const int ra = (wr * 64 + i * 16 + fr) * 4 + fk;
            fah[i] = LAh[ra]; fam[i] = LAm[ra];
            const int rb = (wc * 64 + i * 16 + fr) * 4 + fk;
            fbh[i] = LBh[rb]; fbm[i] = LBm[rb];
        }
#pragma unroll
        for (int i = 0; i < 4; ++i)
#pragma unroll
            for (int j = 0; j < 4; ++j)
                acc[i][j] = __builtin_amdgcn_mfma_f32_16x16x32_bf16(fah[i], fbh[j], acc[i][j], 0, 0, 0);
#pragma unroll
        for (int i = 0; i < 4; ++i)
#pragma unroll
            for (int j = 0; j < 4; ++j)
                acc[i][j] = __builtin_amdgcn_mfma_f32_16x16x32_bf16(fah[i], fbm[j], acc[i][j], 0, 0, 0);
#pragma unroll
        for (int i = 0; i < 4; ++i)
#pragma unroll
            for (int j = 0; j < 4; ++j)
                acc[i][j] = __builtin_amdgcn_mfma_f32_16x16x32_bf16(fam[i], fbh[j], acc[i][j], 0, 0, 0);
    }

    // ---- epilogue: bias + relu, then layer-2 partials over this wave's 64 cols ----
    // C/D layout: lane holds D[fk*4+r][fr] of each 16x16 frag (guide-verified)
    const int colbase = n0 + wc * 64 + fr;
#pragma unroll
    for (int j = 0; j < 4; ++j) {
        const float bj = B1[colbase + j * 16];
#pragma unroll
        for (int i = 0; i < 4; ++i)
#pragma unroll
            for (int r = 0; r < 4; ++r)
                acc[i][j][r] = fmaxf(acc[i][j][r] + bj, 0.f);
    }

    const int slice = (bid & 7) * 2 + wc;     // 16 col-slices of 64
    float* pbase = ws + ((size_t)slice * NTOK + (m0 + wr * 64 + fk * 4)) * NEXP;
#pragma unroll
    for (int e = 0; e < 8; ++e) {
        const float w20 = W2[e * HID + colbase];
        const float w21 = W2[e * HID + colbase + 16];
        const float w22 = W2[e * HID + colbase + 32];
        const float w23 = W2[e * HID + colbase + 48];
        float pe[16];
#pragma unroll
        for (int i = 0; i < 4; ++i)
#pragma unroll
            for (int r = 0; r < 4; ++r)
                pe[i * 4 + r] = acc[i][0][r] * w20 + acc[i][1][r] * w21 +
                                acc[i][2][r] * w22 + acc[i][3][r] * w23;
#pragma unroll
        for (int m = 1; m <= 8; m <<= 1)
#pragma unroll
            for (int q = 0; q < 16; ++q)
                pe[q] += __shfl_xor(pe[q], m, 64);
        if (fr == 0) {
#pragma unroll
            for (int i = 0; i < 4; ++i)
#pragma unroll
                for (int r = 0; r < 4; ++r)
                    pbase[(size_t)(i * 16 + r) * NEXP + e] = pe[i * 4 + r];
        }
    }
}

// ---------------- Router: sum partials, softmax, top-2, scatter, flag ties ----
__global__ __launch_bounds__(256) void router2_kernel(
    float* __restrict__ ws, const float* __restrict__ B2, float* __restrict__ out)
{
    const int t = blockIdx.x * 256 + threadIdx.x;
    float lg[8];
#pragma unroll
    for (int e = 0; e < 8; ++e) lg[e] = 0.f;
#pragma unroll
    for (int s = 0; s < 16; ++s) {     // fixed slice order -> deterministic
        const float* p = ws + ((size_t)s * NTOK + t) * NEXP;
        f32x4 v0 = *(const f32x4*)p;
        f32x4 v1 = *(const f32x4*)(p + 4);
        lg[0] += v0.x; lg[1] += v0.y; lg[2] += v0.z; lg[3] += v0.w;
        lg[4] += v1.x; lg[5] += v1.y; lg[6] += v1.z; lg[7] += v1.w;
    }
#pragma unroll
    for (int e = 0; e < 8; ++e) lg[e] += B2[e];

    float mx = lg[0];
#pragma unroll
    for (int e = 1; e < 8; ++e) mx = fmaxf(mx, lg[e]);
    float pr[8], s = 0.f;
#pragma unroll
    for (int e = 0; e < 8; ++e) { pr[e] = expf(lg[e] - mx); s += pr[e]; }
    const float inv = 1.f / s;
#pragma unroll
    for (int e = 0; e < 8; ++e) pr[e] *= inv;

    // top-3 (strict > : lowest index wins exact ties, matching lax.top_k)
    int e1 = 0; float p1 = pr[0];
#pragma unroll
    for (int e = 1; e < 8; ++e) if (pr[e] > p1) { p1 = pr[e]; e1 = e; }
    int e2 = -1; float p2 = -1.f;
#pragma unroll
    for (int e = 0; e < 8; ++e) if (e != e1 && pr[e] > p2) { p2 = pr[e]; e2 = e; }
    float p3 = -1.f;
#pragma unroll
    for (int e = 0; e < 8; ++e) if (e != e1 && e != e2 && pr[e] > p3) p3 = pr[e];

    const float invs = 1.f / (p1 + p2);
    float* rp = out + RP_OFF + (size_t)t * NEXP;
    f32x4 o0 = {pr[0], pr[1], pr[2], pr[3]};
    f32x4 o1 = {pr[4], pr[5], pr[6], pr[7]};
    *(f32x4*)rp = o0; *(f32x4*)(rp + 4) = o1;

    const size_t base = (size_t)t * NEXP;
    out[DISP_OFF + (base + e1) * CAP] = 1.0f;
    out[DISP_OFF + (base + e2) * CAP] = 1.0f;
    out[COMB_OFF + (base + e1) * CAP] = p1 * invs;
    out[COMB_OFF + (base + e2) * CAP] = p2 * invs;

    // near-tie at the rank2/rank3 boundary -> exact fp32 recompute later
    if (p2 - p3 < PGAP_TAU) {
        int* cnt = (int*)(ws + PART_F);
        int idx = atomicAdd(cnt, 1);
        if (idx < MAXFIX)
            ((unsigned*)(cnt + 1))[idx] = ((unsigned)t << 8) | ((unsigned)e1 << 4) | (unsigned)e2;
    }
}

// ---------------- Fixup: exact fp32 recompute of flagged tokens ----------------
__global__ __launch_bounds__(256) void fixup_kernel(
    const float* __restrict__ X,  const float* __restrict__ W1,
    const float* __restrict__ B1, const float* __restrict__ W2,
    const float* __restrict__ B2, float* __restrict__ ws, float* __restrict__ out)
{
    __shared__ float xs[HID];
    __shared__ float hs[HID];
    __shared__ float lgs[NEXP];
    const int tid = threadIdx.x;
    const int cnt0 = ((const int*)(ws + PART_F))[0];
    const int cnt = cnt0 < MAXFIX ? cnt0 : MAXFIX;
    const unsigned* wl = (const unsigned*)(ws + PART_F + 1);

    for (int idx = blockIdx.x; idx < cnt; idx += 32) {
        const unsigned ent = wl[idx];
        const int t = (int)(ent >> 8), oe1 = (ent >> 4) & 15, oe2 = ent & 15;
        for (int i = tid; i < HID; i += 256) xs[i] = X[(size_t)t * HID + i];
        __syncthreads();
        // h rows 4*tid..+3, ascending-k fp32 (matches reference/XLA order)
        const float* w0p = W1 + (size_t)(tid * 4 + 0) * HID;
        const float* w1p = W1 + (size_t)(tid * 4 + 1) * HID;
        const float* w2p = W1 + (size_t)(tid * 4 + 2) * HID;
        const float* w3p = W1 + (size_t)(tid * 4 + 3) * HID;
        float a0 = 0.f, a1 = 0.f, a2 = 0.f, a3 = 0.f;
#pragma unroll 4
        for (int k = 0; k < HID; ++k) {
            const float xk = xs[k];
            a0 = fmaf(xk, w0p[k], a0);
            a1 = fmaf(xk, w1p[k], a1);
            a2 = fmaf(xk, w2p[k], a2);
            a3 = fmaf(xk, w3p[k], a3);
        }
        hs[tid * 4 + 0] = fmaxf(a0 + B1[tid * 4 + 0], 0.f);
        hs[tid * 4 + 1] = fmaxf(a1 + B1[tid * 4 + 1], 0.f);
        hs[tid * 4 + 2] = fmaxf(a2 + B1[tid * 4 + 2], 0.f);
        hs[tid * 4 + 3] = fmaxf(a3 + B1[tid * 4 + 3], 0.f);
        __syncthreads();
        if (tid < 8) {
            float sl = 0.f;
            const float* wp = W2 + (size_t)tid * HID;
            for (int k = 0; k < HID; ++k) sl = fmaf(hs[k], wp[k], sl);
            lgs[tid] = sl + B2[tid];
        }
        __syncthreads();
        if (tid == 0) {
            float mx = lgs[0];
#pragma unroll
            for (int e = 1; e < 8; ++e) mx = fmaxf(mx, lgs[e]);
            float pr[8], s = 0.f;
#pragma unroll
            for (int e = 0; e < 8; ++e) { pr[e] = expf(lgs[e] - mx); s += pr[e]; }
            const float inv = 1.f / s;
#pragma unroll
            for (int e = 0; e < 8; ++e) pr[e] *= inv;
            int e1 = 0; float p1v = pr[0];
#pragma unroll
            for (int e = 1; e < 8; ++e) if (pr[e] > p1v) { p1v = pr[e]; e1 = e; }
            int e2 = -1; float p2v = -1.f;
#pragma unroll
            for (int e = 0; e < 8; ++e) if (e != e1 && pr[e] > p2v) { p2v = pr[e]; e2 = e; }
            const float invs = 1.f / (p1v + p2v);
            const size_t base = (size_t)t * NEXP;
            out[DISP_OFF + (base + oe1) * CAP] = 0.f;   // clear old selection
            out[DISP_OFF + (base + oe2) * CAP] = 0.f;
            out[COMB_OFF + (base + oe1) * CAP] = 0.f;
            out[COMB_OFF + (base + oe2) * CAP] = 0.f;
            out[DISP_OFF + (base + e1) * CAP] = 1.0f;   // write exact selection
            out[DISP_OFF + (base + e2) * CAP] = 1.0f;
            out[COMB_OFF + (base + e1) * CAP] = p1v * invs;
            out[COMB_OFF + (base + e2) * CAP] = p2v * invs;
            float* rp = out + RP_OFF + base;
#pragma unroll
            for (int e = 0; e < 8; ++e) rp[e] = pr[e];
        }
        __syncthreads();
    }
}

// ---------------- Aux loss (reads final router_probs) ----------------
__global__ __launch_bounds__(256) void aux_kernel(float* __restrict__ out)
{
    __shared__ float sm[NEXP][257];
    const int tid = threadIdx.x;
    float s[NEXP];
#pragma unroll
    for (int e = 0; e < 8; ++e) s[e] = 0.f;
    const float* rp = out + RP_OFF;
    for (int t = tid; t < NTOK; t += 256) {
        f32x4 v0 = *(const f32x4*)&rp[(size_t)t * NEXP];
        f32x4 v1 = *(const f32x4*)&rp[(size_t)t * NEXP + 4];
        s[0] += v0.x; s[1] += v0.y; s[2] += v0.z; s[3] += v0.w;
        s[4] += v1.x; s[5] += v1.y; s[6] += v1.z; s[7] += v1.w;
    }
#pragma unroll
    for (int e = 0; e < 8; ++e) sm[e][tid] = s[e];
    __syncthreads();
    for (int st = 128; st > 0; st >>= 1) {
        if (tid < st) {
#pragma unroll
            for (int e = 0; e < 8; ++e) sm[e][tid] += sm[e][tid + st];
        }
        __syncthreads();
    }
    if (tid == 0) {
        float loss = 0.f;
#pragma unroll
        for (int e = 0; e < 8; ++e) {
            float m = sm[e][0] * (1.0f / NTOK);
            loss += m * logf(m * (float)NEXP + 1e-9f);
        }
        out[AUX_OFF] = loss;
    }
}

extern "C" void kernel_launch(void* const* d_in, const int* in_sizes, int n_in,
                              void* d_out, int out_size, void* d_ws, size_t ws_size,
                              hipStream_t stream)
{
    const float* x  = (const float*)d_in[0];   // [2,2048,1024]
    const float* w1 = (const float*)d_in[1];   // [1024,1024]
    const float* b1 = (const float*)d_in[2];   // [1024]
    const float* w2 = (const float*)d_in[3];   // [8,1024]
    const float* b2 = (const float*)d_in[4];   // [8]
    float* out = (float*)d_out;
    float* ws  = (float*)d_ws;                 // part 2MB + cnt + worklist

    // 512 blocks, all co-resident (2/CU): 256 MFMA-GEMM tiles + 256 zero slices.
    fused_kernel<<<512, 256, 0, stream>>>(x, w1, b1, w2, ws, out);
    router2_kernel<<<16, 256, 0, stream>>>(ws, b2, out);
    fixup_kernel<<<32, 256, 0, stream>>>(x, w1, b1, w2, b2, ws, out);
    aux_kernel<<<1, 256, 0, stream>>>(out);
}